// Round 15
// baseline (33.428 us; speedup 1.0000x reference)
//
#include <hip/hip_runtime.h>
#include <math.h>

// Problem constants: N=12000, NEI=32, K=8, D=64
#define NPTS 12000
#define NNEI 32
#define KK   8
#define DD   64

// Round 15: TWO-kernel pipeline (no grid sync anywhere).
//  - packW merged into passA ("passAW"): each wave stages its own W[k] in
//    4-row chunks, COALESCED global float4 loads (1KB/instr) -> private LDS
//    slice (reuses its xtr[k] plane, row stride 68: write = min 8 words/bank,
//    read = 2-way, both free) -> fragment reads -> hi/lo bf16 pack.
//    Wave-private => zero new barriers. Avoids R5's 256B-stride scatter.
//  - km row + exp(scales) recomputed per block (cheap, wave-private kmL).
//  - R14 lesson: cooperative grid.sync deadlocked (VGPR > 128 broke
//    co-residency and validation didn't catch it) -- fusion abandoned.
// Everything else identical to R12 (best proven: 30.7us).

typedef __bf16 bf16x8 __attribute__((ext_vector_type(8)));
typedef float  f32x4  __attribute__((ext_vector_type(4)));

#define MFMA16(A, B, C) __builtin_amdgcn_mfma_f32_16x16x32_bf16((A), (B), (C), 0, 0, 0)

__device__ __forceinline__ void pack8(float4 u, float4 v, bf16x8& h, bf16x8& l) {
    float a[8] = {u.x, u.y, u.z, u.w, v.x, v.y, v.z, v.w};
    #pragma unroll
    for (int i = 0; i < 8; ++i) {
        __bf16 hh = (__bf16)a[i];
        h[i] = hh;
        l[i] = (__bf16)(a[i] - (float)hh);
    }
}

__device__ __forceinline__ float dot4(float4 a, float4 b) {
    return a.x * b.x + a.y * b.y + a.z * b.z + a.w * b.w;
}

// ---------------------------------------------------------------- passAW ---
__launch_bounds__(512)
__global__ void passAW_kernel(const float* __restrict__ x,
                              const float* __restrict__ kp,
                              const float* __restrict__ W,
                              const float* __restrict__ b,
                              const float* __restrict__ scales,
                              float* __restrict__ F) {
    __shared__ float xtr[KK][16][68];   // per-wave plane: W staging, then xtr
    __shared__ float kmL[KK][DD];       // per-wave km row (wave-private use)
    __shared__ float disl[16][12];      // u = 1/z per (point, k)

    const int t    = threadIdx.x;
    const int k    = t >> 6;            // wave index == kernel index
    const int lane = t & 63;
    const int c    = lane & 15;
    const int g    = lane >> 4;
    const int pbase = blockIdx.x * 16;

    // ---- km row for this wave's k: (kernels*metric)[k][:] (wave-private) ----
    {
        float spv = (lane == 0) ? 0.f : kp[k * DD + lane];   // kp[:,0]==0
        float ss = spv * spv;
        #pragma unroll
        for (int off = 32; off > 0; off >>= 1) ss += __shfl_xor(ss, off);
        float nrm = sqrtf(fmaxf(ss, 1e-8f));
        float e  = __expf(nrm);
        float ei = 1.0f / e;
        kmL[k][lane] = (lane == 0) ? 0.5f * (e + ei)
                                   : -(0.5f * (e - ei) / nrm) * spv;
    }
    const float es = __expf(scales[k]);
    float bnt[4];
    #pragma unroll
    for (int nt = 0; nt < 4; ++nt) bnt[nt] = b[k * DD + nt * 16 + c];

    // ---- W[k] fragments: coalesced global -> private LDS slice -> pack ----
    // chunk nt = rows [nt*16, nt*16+16) of W[k]; flat float4 f = i*64+lane
    // -> row i*4+g, colword c*4.  Fragment read: row c, words ks*32+g*8(+4).
    bf16x8 Wh[4][2], Wl[4][2];
    {
        const float4* Wc0 = (const float4*)(W + (size_t)k * DD * DD);
        #pragma unroll
        for (int nt = 0; nt < 4; ++nt) {
            const float4* Wc = Wc0 + nt * 256;
            float4 wv0 = Wc[          lane];
            float4 wv1 = Wc[ 64 +     lane];
            float4 wv2 = Wc[128 +     lane];
            float4 wv3 = Wc[192 +     lane];
            *(float4*)&xtr[k][ 0 + g][c * 4] = wv0;
            *(float4*)&xtr[k][ 4 + g][c * 4] = wv1;
            *(float4*)&xtr[k][ 8 + g][c * 4] = wv2;
            *(float4*)&xtr[k][12 + g][c * 4] = wv3;
            #pragma unroll
            for (int ks = 0; ks < 2; ++ks) {
                float4 f0 = *(const float4*)&xtr[k][c][ks * 32 + g * 8];
                float4 f1 = *(const float4*)&xtr[k][c][ks * 32 + g * 8 + 4];
                pack8(f0, f1, Wh[nt][ks], Wl[nt][ks]);
            }
        }
    }

    // ---- x row chunks ----
    float4 u0, u1, u2, u3;
    {
        const float* xr = x + (size_t)(pbase + c) * DD + g * 8;
        u0 = *(const float4*)(xr +  0);
        u1 = *(const float4*)(xr +  4);
        u2 = *(const float4*)(xr + 32);
        u3 = *(const float4*)(xr + 36);
    }

    // ---- inner product <x_row, km_k>; softmax numerator u = 1/z (exact) ----
    {
        const float4* km4 = (const float4*)&kmL[k][0];
        float ip = dot4(u0, km4[g * 2 + 0]) + dot4(u1, km4[g * 2 + 1])
                 + dot4(u2, km4[g * 2 + 8]) + dot4(u3, km4[g * 2 + 9]);
        ip += __shfl_xor(ip, 16);
        ip += __shfl_xor(ip, 32);   // sum the 4 g-group partials
        if (g == 0) {
            float nc = fmaxf(ip, 1.0f + 1e-7f);
            // exp(-arccosh(nc)) = 1 / (nc + sqrt(nc^2 - 1))  -- exact
            disl[c][k] = 1.0f / (nc + sqrtf(nc * nc - 1.0f));
        }
    }

    // ---- A fragments ----
    bf16x8 Ah[2], Al[2];
    pack8(u0, u1, Ah[0], Al[0]);
    pack8(u2, u3, Ah[1], Al[1]);

    // ---- MFMAs: Y only (24) ----
    f32x4 accY[4];
    #pragma unroll
    for (int nt = 0; nt < 4; ++nt) accY[nt] = (f32x4){0.f, 0.f, 0.f, 0.f};
    #pragma unroll
    for (int ks = 0; ks < 2; ++ks)
        #pragma unroll
        for (int nt = 0; nt < 4; ++nt) {
            accY[nt] = MFMA16(Ah[ks], Wh[nt][ks], accY[nt]);
            accY[nt] = MFMA16(Ah[ks], Wl[nt][ks], accY[nt]);
            accY[nt] = MFMA16(Al[ks], Wh[nt][ks], accY[nt]);
        }

    // ---- epilogue: per-point stats (C layout: row p=g*4+rr, col o=nt*16+c) ----
    float yv[4][4], sall[4];
    #pragma unroll
    for (int rr = 0; rr < 4; ++rr) {
        float s = 0.f;
        #pragma unroll
        for (int nt = 0; nt < 4; ++nt) {
            float y = accY[nt][rr] + bnt[nt];
            yv[nt][rr] = y;
            s += y * y;
        }
        sall[rr] = s;
    }
    #pragma unroll
    for (int m = 1; m <= 8; m <<= 1)
        #pragma unroll
        for (int rr = 0; rr < 4; ++rr) sall[rr] += __shfl_xor(sall[rr], m);
    float y0[4];
    #pragma unroll
    for (int rr = 0; rr < 4; ++rr) y0[rr] = __shfl(yv[0][rr], lane & 48);

    #pragma unroll
    for (int rr = 0; rr < 4; ++rr) {
        const int p = g * 4 + rr;
        float nar2 = fmaxf(sall[rr] - y0[rr] * y0[rr], 1e-8f);
        float time = es / (1.0f + __expf(-y0[rr])) + 1.0001f;
        float s3   = sqrtf((time * time - 1.0f) / nar2);
        #pragma unroll
        for (int nt = 0; nt < 4; ++nt) {
            float v = yv[nt][rr] * s3;
            if (nt == 0 && c == 0) v = time;
            xtr[k][p][nt * 16 + c] = v;   // overwrites this wave's own staging
        }
    }
    __syncthreads();

    // ---- combine: wave k handles points {2k, 2k+1} ----
    #pragma unroll
    for (int pi = 0; pi < 2; ++pi) {
        const int p = k * 2 + pi;
        float uk[KK];
        float sum = 0.f;
        #pragma unroll
        for (int q = 0; q < KK; ++q) { uk[q] = disl[p][q]; sum += uk[q]; }
        float inv = 1.0f / sum;
        float agg = 0.f;
        #pragma unroll
        for (int q = 0; q < KK; ++q) agg += uk[q] * inv * xtr[q][p][lane];

        float vv = (lane == 0) ? -agg * agg : agg * agg;
        #pragma unroll
        for (int m = 32; m > 0; m >>= 1) vv += __shfl_xor(vv, m);
        float den = sqrtf(fmaxf(fabsf(vv), 1e-8f));
        F[(size_t)(pbase + p) * DD + lane] = agg / den;
    }
}

// ---------------------------------------------------------------- pass B ---
__launch_bounds__(256)
__global__ void passB_kernel(const float* __restrict__ F,
                             const int* __restrict__ nei,
                             const int* __restrict__ mask,
                             float* __restrict__ out) {
    const int t    = threadIdx.x;
    const int wave = t >> 6;
    const int lane = t & 63;
    const int c    = lane & 15;   // col quad: o = 4c..4c+3
    const int g    = lane >> 4;   // m sub-index
    const int n    = blockIdx.x * 4 + wave;

    // one coalesced 256B fetch per wave: lanes 0..31 nei row, 32..63 mask row
    int vsrc;
    if (lane < 32) vsrc = nei[n * NNEI + lane];
    else           vsrc = mask[n * NNEI + (lane - 32)];

    const float4* F4 = (const float4*)F;
    float4 acc = {0.f, 0.f, 0.f, 0.f};
    #pragma unroll
    for (int mq = 0; mq < 8; ++mq) {
        int   m   = mq * 4 + g;
        int   j   = __shfl(vsrc, m);
        float wgt = (float)__shfl(vsrc, 32 + m) + 1e-4f;
        float4 v  = F4[(size_t)j * 16 + c];
        acc.x += wgt * v.x; acc.y += wgt * v.y;
        acc.z += wgt * v.z; acc.w += wgt * v.w;
    }
    // reduce over the 4 m-subgroups (lanes xor 16, 32)
    #pragma unroll
    for (int m = 16; m <= 32; m <<= 1) {
        acc.x += __shfl_xor(acc.x, m); acc.y += __shfl_xor(acc.y, m);
        acc.z += __shfl_xor(acc.z, m); acc.w += __shfl_xor(acc.w, m);
    }
    // lorentz inner: minus sign on o==0 (lane c==0, component .x)
    float s = acc.x * acc.x + acc.y * acc.y + acc.z * acc.z + acc.w * acc.w;
    if (c == 0) s -= 2.0f * acc.x * acc.x;
    #pragma unroll
    for (int m = 1; m <= 8; m <<= 1) s += __shfl_xor(s, m);
    float den = sqrtf(fmaxf(fabsf(s), 1e-8f));
    if (g == 0) {
        float4 rr = {acc.x / den, acc.y / den, acc.z / den, acc.w / den};
        ((float4*)out)[(size_t)n * 16 + c] = rr;
    }
}

// ---------------------------------------------------------------- launch ---
extern "C" void kernel_launch(void* const* d_in, const int* in_sizes, int n_in,
                              void* d_out, int out_size, void* d_ws, size_t ws_size,
                              hipStream_t stream) {
    const float* x      = (const float*)d_in[0];  // (12000, 64) f32
    const int*   nei    = (const int*)  d_in[1];  // (12000, 32) int32
    const int*   mask   = (const int*)  d_in[2];  // (12000, 32) int32
    const float* kp     = (const float*)d_in[3];  // (8, 64) f32
    const float* W      = (const float*)d_in[4];  // (8, 64, 64) f32
    const float* b      = (const float*)d_in[5];  // (8, 64) f32
    const float* scales = (const float*)d_in[6];  // (8,) f32
    float*       out    = (float*)d_out;          // (12000, 64) f32

    // ws: F (N*D f32) only
    const size_t needed = (size_t)(NPTS * DD) * sizeof(float);
    if (ws_size < needed) return;
    float* F = (float*)d_ws;

    passAW_kernel<<<NPTS / 16, 512, 0, stream>>>(x, kp, W, b, scales, F);
    passB_kernel<<<NPTS / 4, 256, 0, stream>>>(F, nei, mask, out);
}